// Round 5
// baseline (145.304 us; speedup 1.0000x reference)
//
#include <hip/hip_runtime.h>
#include <hip/hip_bf16.h>

// GAT fused kernel for MI355X (gfx950).  B=32, N=1024, F_IN=F_OUT=64, ALPHA=0.2
//
// Round 5: PROFILE-SURFACING ROUND. r4 isolated attn ~= 43.5us (4x the
// instruction/BW model; r3 proved not adj-BW-bound). Harness 75us poison
// fills hide our kernels from rocprof top-5, so attn now runs its whole body
// REP=2 times inside ONE dispatch (~87us -> top of profile, full counters).
// Rep 0 stores to a dead ws region (prevents DCE, rule #17), rep 1 to d_out.
// Body otherwise identical to r4. Counter signatures decide next fix:
//   FETCH >> 270MB & VGPR=128 -> spill; VALUBusy>70% -> VALU-bound;
//   all low -> latency-bound.

#define B_  32
#define N_  1024
#define F_  64
#define REP 2

typedef __attribute__((ext_vector_type(8))) short  short8;
typedef __attribute__((ext_vector_type(4))) float  floatx4;

__device__ __forceinline__ short f2bf(float x) {
    unsigned u = __float_as_uint(x);
    u += 0x7fff + ((u >> 16) & 1);   // RNE
    return (short)(u >> 16);
}

// ---------------- Kernel 1: prep ----------------
__global__ __launch_bounds__(256) void gat_prep(
    const float* __restrict__ nf, const float* __restrict__ W, const float* __restrict__ a,
    float* __restrict__ f1, float* __restrict__ f2, short* __restrict__ h_swz)
{
    const int wave = threadIdx.x >> 6;
    const int lane = threadIdx.x & 63;
    const long long row0 = (long long)blockIdx.x * 16 + wave * 4;

    const float* nf0 = nf + row0 * F_;
    float acc0 = 0.f, acc1 = 0.f, acc2 = 0.f, acc3 = 0.f;
    #pragma unroll 8
    for (int k = 0; k < F_; ++k) {
        float wk = W[k * F_ + lane];
        acc0 = fmaf(nf0[k],          wk, acc0);
        acc1 = fmaf(nf0[F_ + k],     wk, acc1);
        acc2 = fmaf(nf0[2 * F_ + k], wk, acc2);
        acc3 = fmaf(nf0[3 * F_ + k], wk, acc3);
    }
    const float a1 = a[lane], a2 = a[F_ + lane];

    float accs[4] = {acc0, acc1, acc2, acc3};
    #pragma unroll
    for (int r = 0; r < 4; ++r) {
        float v  = accs[r];
        float s1 = v * a1, s2 = v * a2;
        #pragma unroll
        for (int off = 32; off >= 1; off >>= 1) {
            s1 += __shfl_xor(s1, off, 64);
            s2 += __shfl_xor(s2, off, 64);
        }
        long long row = row0 + r;
        if (lane == 0) { f1[row] = s1; f2[row] = s2; }
        // swizzled bf16 store: B-frag layout for mfma_f32_16x16x32_bf16.
        int jl = (int)(row & (N_ - 1));
        int k  = jl & 31;
        int n  = lane & 15, fg = lane >> 4;
        int lp = n | ((k >> 3) << 4), e = k & 7;
        long long gc = row >> 5;   // global 32-row chunk id
        h_swz[(gc * 4 + fg) * 512 + lp * 8 + e] = f2bf(v);
    }
}

// ---------------- Kernel 2: fused attention (REP-instrumented) ----------------
// grid = B * (N/16) blocks, 256 threads = 4 waves.
// All 4 waves own the SAME 16 i-rows; wave w covers j in [w*256, w*256+256).
__global__ __launch_bounds__(256, 4) void gat_attn(
    const int* __restrict__ adj, const float* __restrict__ f1g,
    const float* __restrict__ f2g, const short* __restrict__ h_swz,
    float* __restrict__ outp, float* __restrict__ dummy)
{
    __shared__ float part[4][64][17];
    __shared__ float srow[4][16];

    const int wave = threadIdx.x >> 6;
    const int lane = threadIdx.x & 63;
    const int b  = blockIdx.x >> 6;        // 64 i-groups per batch
    const int ig = blockIdx.x & 63;
    const int i_base = ig * 16;
    const int iw = lane & 15;              // A-frag row within 16
    const int kg = lane >> 4;              // A-frag k-group (8 k's each)
    const int i  = i_base + iw;
    const int j0 = wave * 256;             // this wave's j-range

    const float f1i = f1g[b * N_ + i];
    const int*   adjrow = adj + ((long long)b * N_ + i) * N_ + j0 + kg * 8;
    const float* f2b    = f2g + b * N_ + j0 + kg * 8;
    const short* hb     = h_swz + (long long)b * 65536 + wave * 16384 + lane * 8;

    for (int rep = 0; rep < REP; ++rep) {
        floatx4 acc0 = {0.f,0.f,0.f,0.f}, acc1 = {0.f,0.f,0.f,0.f};
        floatx4 acc2 = {0.f,0.f,0.f,0.f}, acc3 = {0.f,0.f,0.f,0.f};
        float s0 = 0.f, s1 = 0.f;

        // prologue: issue jc=0 loads
        int4    nA  = *(const int4*)(adjrow);
        int4    nB  = *(const int4*)(adjrow + 4);
        floatx4 nfA = *(const floatx4*)(f2b);
        floatx4 nfB = *(const floatx4*)(f2b + 4);
        short8  nh0 = *(const short8*)(hb);
        short8  nh1 = *(const short8*)(hb + 512);
        short8  nh2 = *(const short8*)(hb + 1024);
        short8  nh3 = *(const short8*)(hb + 1536);

        #pragma unroll
        for (int jc = 0; jc < 8; ++jc) {
            int4 cA = nA, cB = nB;
            floatx4 cfA = nfA, cfB = nfB;
            short8 c0 = nh0, c1 = nh1, c2 = nh2, c3 = nh3;
            if (jc < 7) {                   // issue jc+1 loads NOW
                const int off = (jc + 1) * 32;
                nA  = *(const int4*)(adjrow + off);
                nB  = *(const int4*)(adjrow + off + 4);
                nfA = *(const floatx4*)(f2b + off);
                nfB = *(const floatx4*)(f2b + off + 4);
                const short* hc = hb + (jc + 1) * 2048;
                nh0 = *(const short8*)(hc);
                nh1 = *(const short8*)(hc + 512);
                nh2 = *(const short8*)(hc + 1024);
                nh3 = *(const short8*)(hc + 1536);
            }

            int   am[8] = {cA.x, cA.y, cA.z, cA.w, cB.x, cB.y, cB.z, cB.w};
            float fv[8] = {cfA[0], cfA[1], cfA[2], cfA[3], cfB[0], cfB[1], cfB[2], cfB[3]};
            short8 afrag;
            #pragma unroll
            for (int e = 0; e < 8; ++e) {
                float x  = f1i + fv[e];
                x        = fmaxf(x, 0.2f * x);              // leaky relu
                float pe = am[e] ? __expf(x) : 0.f;         // masked exp
                if (e & 1) s1 += pe; else s0 += pe;
                afrag[e] = f2bf(pe);
            }

            acc0 = __builtin_amdgcn_mfma_f32_16x16x32_bf16(afrag, c0, acc0, 0, 0, 0);
            acc1 = __builtin_amdgcn_mfma_f32_16x16x32_bf16(afrag, c1, acc1, 0, 0, 0);
            acc2 = __builtin_amdgcn_mfma_f32_16x16x32_bf16(afrag, c2, acc2, 0, 0, 0);
            acc3 = __builtin_amdgcn_mfma_f32_16x16x32_bf16(afrag, c3, acc3, 0, 0, 0);
        }

        float s_lane = s0 + s1;
        // per-wave row-subrange denominator: sum over the 4 kg lanes of row iw
        s_lane += __shfl_xor(s_lane, 16, 64);
        s_lane += __shfl_xor(s_lane, 32, 64);
        if (lane < 16) srow[wave][lane] = s_lane;

        floatx4 accs[4] = {acc0, acc1, acc2, acc3};
        #pragma unroll
        for (int fg = 0; fg < 4; ++fg)
            #pragma unroll
            for (int r = 0; r < 4; ++r)
                part[wave][lane][fg * 4 + r] = accs[fg][r];
        __syncthreads();

        // rep 0 -> dead ws sink (keeps the body live, rule #17); last rep -> out
        float* obase = (rep == REP - 1) ? outp : dummy;
        const int fg = wave;
        float* orow = obase + ((long long)b * N_ + i_base) * F_;
        #pragma unroll
        for (int r = 0; r < 4; ++r) {
            const int idx  = fg * 4 + r;
            const int rloc = kg * 4 + r;
            float tot  = part[0][lane][idx] + part[1][lane][idx]
                       + part[2][lane][idx] + part[3][lane][idx];
            float sden = srow[0][rloc] + srow[1][rloc] + srow[2][rloc] + srow[3][rloc];
            float v = tot / sden;
            v = v > 0.f ? v : (__expf(v) - 1.f);    // ELU (alpha=1)
            orow[(long long)rloc * F_ + fg * 16 + iw] = v;
        }
        __syncthreads();   // part[]/srow[] reused next rep
    }
}

extern "C" void kernel_launch(void* const* d_in, const int* in_sizes, int n_in,
                              void* d_out, int out_size, void* d_ws, size_t ws_size,
                              hipStream_t stream) {
    const float* nf  = (const float*)d_in[0];
    const int*   adj = (const int*)d_in[1];     // bool -> int32 per harness
    const float* W   = (const float*)d_in[2];
    const float* a   = (const float*)d_in[3];
    float* out = (float*)d_out;

    char* ws = (char*)d_ws;
    float* f1      = (float*)ws;                          // 128KB
    float* f2      = (float*)(ws + 131072);               // 128KB
    short* h_swz   = (short*)(ws + 262144);               // 4MB
    float* dummy   = (float*)(ws + 262144 + 4194304);     // 8MB dead probe sink

    hipLaunchKernelGGL(gat_prep, dim3(B_ * N_ / 16), dim3(256), 0, stream,
                       nf, W, a, f1, f2, h_swz);
    hipLaunchKernelGGL(gat_attn, dim3(B_ * (N_ / 16)), dim3(256), 0, stream,
                       adj, f1, f2, h_swz, out, dummy);
}

// Round 6
// 60.903 us; speedup vs baseline: 2.3858x; 2.3858x over previous
//
#include <hip/hip_runtime.h>
#include <hip/hip_bf16.h>

// GAT fused kernel for MI355X (gfx950).  B=32, N=1024, F_IN=F_OUT=64, ALPHA=0.2
//
// Round 6: r5 counters: MfmaUtil 2.4%, VALUBusy 10%, HBM 23%, occ 40% => pure
// latency stall; WRITE_SIZE 182MB (vs 16 nominal) + VGPR=64 => compiler spilled
// the prefetch set to scratch (launch_bounds(256,4) squeeze). Fix by structure:
//   phase 1: stream adj+f2 ONLY (2 half-passes x 16 independent int4 loads,
//            fill-kernel-like MLP), keep all 8 P-fragments in registers;
//   phase 2: h loads (L2-hot) + 32 MFMAs, 2-jc chunks.
// launch_bounds(256,2) so regs float to ~120 without spill. REP probe removed.

#define B_  32
#define N_  1024
#define F_  64

typedef __attribute__((ext_vector_type(8))) short  short8;
typedef __attribute__((ext_vector_type(4))) float  floatx4;

__device__ __forceinline__ short f2bf(float x) {
    unsigned u = __float_as_uint(x);
    u += 0x7fff + ((u >> 16) & 1);   // RNE
    return (short)(u >> 16);
}

// ---------------- Kernel 1: prep ----------------
__global__ __launch_bounds__(256) void gat_prep(
    const float* __restrict__ nf, const float* __restrict__ W, const float* __restrict__ a,
    float* __restrict__ f1, float* __restrict__ f2, short* __restrict__ h_swz)
{
    const int wave = threadIdx.x >> 6;
    const int lane = threadIdx.x & 63;
    const long long row0 = (long long)blockIdx.x * 16 + wave * 4;

    const float* nf0 = nf + row0 * F_;
    float acc0 = 0.f, acc1 = 0.f, acc2 = 0.f, acc3 = 0.f;
    #pragma unroll 8
    for (int k = 0; k < F_; ++k) {
        float wk = W[k * F_ + lane];
        acc0 = fmaf(nf0[k],          wk, acc0);
        acc1 = fmaf(nf0[F_ + k],     wk, acc1);
        acc2 = fmaf(nf0[2 * F_ + k], wk, acc2);
        acc3 = fmaf(nf0[3 * F_ + k], wk, acc3);
    }
    const float a1 = a[lane], a2 = a[F_ + lane];

    float accs[4] = {acc0, acc1, acc2, acc3};
    #pragma unroll
    for (int r = 0; r < 4; ++r) {
        float v  = accs[r];
        float s1 = v * a1, s2 = v * a2;
        #pragma unroll
        for (int off = 32; off >= 1; off >>= 1) {
            s1 += __shfl_xor(s1, off, 64);
            s2 += __shfl_xor(s2, off, 64);
        }
        long long row = row0 + r;
        if (lane == 0) { f1[row] = s1; f2[row] = s2; }
        // swizzled bf16 store: B-frag layout for mfma_f32_16x16x32_bf16.
        int jl = (int)(row & (N_ - 1));
        int k  = jl & 31;
        int n  = lane & 15, fg = lane >> 4;
        int lp = n | ((k >> 3) << 4), e = k & 7;
        long long gc = row >> 5;   // global 32-row chunk id
        h_swz[(gc * 4 + fg) * 512 + lp * 8 + e] = f2bf(v);
    }
}

// ---------------- Kernel 2: fused attention (2-phase) ----------------
// grid = B * (N/16) blocks, 256 threads = 4 waves.
// All 4 waves own the SAME 16 i-rows; wave w covers j in [w*256, w*256+256).
__global__ __launch_bounds__(256, 2) void gat_attn(
    const int* __restrict__ adj, const float* __restrict__ f1g,
    const float* __restrict__ f2g, const short* __restrict__ h_swz,
    float* __restrict__ outp)
{
    __shared__ float part[4][64][17];
    __shared__ float srow[4][16];

    const int wave = threadIdx.x >> 6;
    const int lane = threadIdx.x & 63;
    const int b  = blockIdx.x >> 6;        // 64 i-groups per batch
    const int ig = blockIdx.x & 63;
    const int i_base = ig * 16;
    const int iw = lane & 15;              // A-frag row within 16
    const int kg = lane >> 4;              // A-frag k-group (8 k's each)
    const int i  = i_base + iw;
    const int j0 = wave * 256;             // this wave's j-range

    const float f1i = f1g[b * N_ + i];
    const int*   adjrow = adj + ((long long)b * N_ + i) * N_ + j0 + kg * 8;
    const float* f2b    = f2g + b * N_ + j0 + kg * 8;
    const short* hb     = h_swz + (long long)b * 65536 + wave * 16384 + lane * 8;

    // ---------- phase 1: stream adjacency, build all 8 P-fragments ----------
    short8 pfr[8];
    float s0 = 0.f, s1 = 0.f;
    #pragma unroll
    for (int half = 0; half < 2; ++half) {
        int4    aA[4], aB[4];
        floatx4 fA[4], fB[4];
        #pragma unroll
        for (int q = 0; q < 4; ++q) {       // 16 independent loads, all in flight
            const int off = (half * 4 + q) * 32;
            aA[q] = *(const int4*)(adjrow + off);
            aB[q] = *(const int4*)(adjrow + off + 4);
            fA[q] = *(const floatx4*)(f2b + off);
            fB[q] = *(const floatx4*)(f2b + off + 4);
        }
        #pragma unroll
        for (int q = 0; q < 4; ++q) {
            const int jc = half * 4 + q;
            int   am[8] = {aA[q].x, aA[q].y, aA[q].z, aA[q].w,
                           aB[q].x, aB[q].y, aB[q].z, aB[q].w};
            float fv[8] = {fA[q][0], fA[q][1], fA[q][2], fA[q][3],
                           fB[q][0], fB[q][1], fB[q][2], fB[q][3]};
            short8 afrag;
            #pragma unroll
            for (int e = 0; e < 8; ++e) {
                float x  = f1i + fv[e];
                x        = fmaxf(x, 0.2f * x);              // leaky relu
                float pe = am[e] ? __expf(x) : 0.f;         // masked exp
                if (e & 1) s1 += pe; else s0 += pe;
                afrag[e] = f2bf(pe);
            }
            pfr[jc] = afrag;
        }
    }

    // ---------- phase 2: h loads (L2-hot) + MFMA, 2-jc chunks ----------
    floatx4 acc0 = {0.f,0.f,0.f,0.f}, acc1 = {0.f,0.f,0.f,0.f};
    floatx4 acc2 = {0.f,0.f,0.f,0.f}, acc3 = {0.f,0.f,0.f,0.f};
    #pragma unroll
    for (int jc = 0; jc < 8; jc += 2) {
        const short* hcA = hb + jc * 2048;
        const short* hcB = hb + (jc + 1) * 2048;
        short8 hA0 = *(const short8*)(hcA);
        short8 hA1 = *(const short8*)(hcA + 512);
        short8 hA2 = *(const short8*)(hcA + 1024);
        short8 hA3 = *(const short8*)(hcA + 1536);
        short8 hB0 = *(const short8*)(hcB);
        short8 hB1 = *(const short8*)(hcB + 512);
        short8 hB2 = *(const short8*)(hcB + 1024);
        short8 hB3 = *(const short8*)(hcB + 1536);

        acc0 = __builtin_amdgcn_mfma_f32_16x16x32_bf16(pfr[jc], hA0, acc0, 0, 0, 0);
        acc1 = __builtin_amdgcn_mfma_f32_16x16x32_bf16(pfr[jc], hA1, acc1, 0, 0, 0);
        acc2 = __builtin_amdgcn_mfma_f32_16x16x32_bf16(pfr[jc], hA2, acc2, 0, 0, 0);
        acc3 = __builtin_amdgcn_mfma_f32_16x16x32_bf16(pfr[jc], hA3, acc3, 0, 0, 0);
        acc0 = __builtin_amdgcn_mfma_f32_16x16x32_bf16(pfr[jc+1], hB0, acc0, 0, 0, 0);
        acc1 = __builtin_amdgcn_mfma_f32_16x16x32_bf16(pfr[jc+1], hB1, acc1, 0, 0, 0);
        acc2 = __builtin_amdgcn_mfma_f32_16x16x32_bf16(pfr[jc+1], hB2, acc2, 0, 0, 0);
        acc3 = __builtin_amdgcn_mfma_f32_16x16x32_bf16(pfr[jc+1], hB3, acc3, 0, 0, 0);
    }

    float s_lane = s0 + s1;
    // per-wave row-subrange denominator: sum over the 4 kg lanes of row iw
    s_lane += __shfl_xor(s_lane, 16, 64);
    s_lane += __shfl_xor(s_lane, 32, 64);
    if (lane < 16) srow[wave][lane] = s_lane;

    floatx4 accs[4] = {acc0, acc1, acc2, acc3};
    #pragma unroll
    for (int fg = 0; fg < 4; ++fg)
        #pragma unroll
        for (int r = 0; r < 4; ++r)
            part[wave][lane][fg * 4 + r] = accs[fg][r];
    __syncthreads();

    // wave w finishes feature-group fg=w for all 16 rows.
    // C layout: value at reg (fg,r) of lane (iw,kg) -> row rloc=kg*4+r, col fg*16+iw
    const int fg = wave;
    float* orow = outp + ((long long)b * N_ + i_base) * F_;
    #pragma unroll
    for (int r = 0; r < 4; ++r) {
        const int idx  = fg * 4 + r;
        const int rloc = kg * 4 + r;
        float tot  = part[0][lane][idx] + part[1][lane][idx]
                   + part[2][lane][idx] + part[3][lane][idx];
        float sden = srow[0][rloc] + srow[1][rloc] + srow[2][rloc] + srow[3][rloc];
        float v = tot / sden;
        v = v > 0.f ? v : (__expf(v) - 1.f);    // ELU (alpha=1)
        orow[(long long)rloc * F_ + fg * 16 + iw] = v;
    }
}

extern "C" void kernel_launch(void* const* d_in, const int* in_sizes, int n_in,
                              void* d_out, int out_size, void* d_ws, size_t ws_size,
                              hipStream_t stream) {
    const float* nf  = (const float*)d_in[0];
    const int*   adj = (const int*)d_in[1];     // bool -> int32 per harness
    const float* W   = (const float*)d_in[2];
    const float* a   = (const float*)d_in[3];
    float* out = (float*)d_out;

    char* ws = (char*)d_ws;
    float* f1    = (float*)ws;                    // 128KB
    float* f2    = (float*)(ws + 131072);         // 128KB
    short* h_swz = (short*)(ws + 262144);         // 4MB

    hipLaunchKernelGGL(gat_prep, dim3(B_ * N_ / 16), dim3(256), 0, stream,
                       nf, W, a, f1, f2, h_swz);
    hipLaunchKernelGGL(gat_attn, dim3(B_ * (N_ / 16)), dim3(256), 0, stream,
                       adj, f1, f2, h_swz, out);
}

// Round 7
// 60.653 us; speedup vs baseline: 2.3957x; 1.0041x over previous
//
#include <hip/hip_runtime.h>
#include <hip/hip_bf16.h>

// GAT fused kernel for MI355X (gfx950).  B=32, N=1024, F_IN=F_OUT=64, ALPHA=0.2
//
// Round 7: occupancy A/B on r6's 2-phase structure. Ledger: r4 (spill, 16
// waves/CU) = 43.5us attn; r6 (no spill, 8 waves/CU) ~= 52us. All pipes <25%
// busy (r5 counters) => latency-bound. Theory T-B: TLPxILP product is the
// limiter. r6 structure has clean live ranges (~97 peak VGPR by hand-count:
// 64 in-flight + 16 pfr + ~15 addr), so (256,4) [VGPR<=128, 4 blocks/CU,
// 16 waves/CU] should fit WITHOUT r4's spill. Only change vs r6: the bound.
// If total stays ~55-61: T-A (adj lane-scatter / TA serialization) confirmed.

#define B_  32
#define N_  1024
#define F_  64

typedef __attribute__((ext_vector_type(8))) short  short8;
typedef __attribute__((ext_vector_type(4))) float  floatx4;

__device__ __forceinline__ short f2bf(float x) {
    unsigned u = __float_as_uint(x);
    u += 0x7fff + ((u >> 16) & 1);   // RNE
    return (short)(u >> 16);
}

// ---------------- Kernel 1: prep ----------------
__global__ __launch_bounds__(256) void gat_prep(
    const float* __restrict__ nf, const float* __restrict__ W, const float* __restrict__ a,
    float* __restrict__ f1, float* __restrict__ f2, short* __restrict__ h_swz)
{
    const int wave = threadIdx.x >> 6;
    const int lane = threadIdx.x & 63;
    const long long row0 = (long long)blockIdx.x * 16 + wave * 4;

    const float* nf0 = nf + row0 * F_;
    float acc0 = 0.f, acc1 = 0.f, acc2 = 0.f, acc3 = 0.f;
    #pragma unroll 8
    for (int k = 0; k < F_; ++k) {
        float wk = W[k * F_ + lane];
        acc0 = fmaf(nf0[k],          wk, acc0);
        acc1 = fmaf(nf0[F_ + k],     wk, acc1);
        acc2 = fmaf(nf0[2 * F_ + k], wk, acc2);
        acc3 = fmaf(nf0[3 * F_ + k], wk, acc3);
    }
    const float a1 = a[lane], a2 = a[F_ + lane];

    float accs[4] = {acc0, acc1, acc2, acc3};
    #pragma unroll
    for (int r = 0; r < 4; ++r) {
        float v  = accs[r];
        float s1 = v * a1, s2 = v * a2;
        #pragma unroll
        for (int off = 32; off >= 1; off >>= 1) {
            s1 += __shfl_xor(s1, off, 64);
            s2 += __shfl_xor(s2, off, 64);
        }
        long long row = row0 + r;
        if (lane == 0) { f1[row] = s1; f2[row] = s2; }
        // swizzled bf16 store: B-frag layout for mfma_f32_16x16x32_bf16.
        int jl = (int)(row & (N_ - 1));
        int k  = jl & 31;
        int n  = lane & 15, fg = lane >> 4;
        int lp = n | ((k >> 3) << 4), e = k & 7;
        long long gc = row >> 5;   // global 32-row chunk id
        h_swz[(gc * 4 + fg) * 512 + lp * 8 + e] = f2bf(v);
    }
}

// ---------------- Kernel 2: fused attention (2-phase) ----------------
// grid = B * (N/16) blocks, 256 threads = 4 waves.
// All 4 waves own the SAME 16 i-rows; wave w covers j in [w*256, w*256+256).
__global__ __launch_bounds__(256, 4) void gat_attn(
    const int* __restrict__ adj, const float* __restrict__ f1g,
    const float* __restrict__ f2g, const short* __restrict__ h_swz,
    float* __restrict__ outp)
{
    __shared__ float part[4][64][17];
    __shared__ float srow[4][16];

    const int wave = threadIdx.x >> 6;
    const int lane = threadIdx.x & 63;
    const int b  = blockIdx.x >> 6;        // 64 i-groups per batch
    const int ig = blockIdx.x & 63;
    const int i_base = ig * 16;
    const int iw = lane & 15;              // A-frag row within 16
    const int kg = lane >> 4;              // A-frag k-group (8 k's each)
    const int i  = i_base + iw;
    const int j0 = wave * 256;             // this wave's j-range

    const float f1i = f1g[b * N_ + i];
    const int*   adjrow = adj + ((long long)b * N_ + i) * N_ + j0 + kg * 8;
    const float* f2b    = f2g + b * N_ + j0 + kg * 8;
    const short* hb     = h_swz + (long long)b * 65536 + wave * 16384 + lane * 8;

    // ---------- phase 1: stream adjacency, build all 8 P-fragments ----------
    short8 pfr[8];
    float s0 = 0.f, s1 = 0.f;
    #pragma unroll
    for (int half = 0; half < 2; ++half) {
        int4    aA[4], aB[4];
        floatx4 fA[4], fB[4];
        #pragma unroll
        for (int q = 0; q < 4; ++q) {       // 16 independent loads, all in flight
            const int off = (half * 4 + q) * 32;
            aA[q] = *(const int4*)(adjrow + off);
            aB[q] = *(const int4*)(adjrow + off + 4);
            fA[q] = *(const floatx4*)(f2b + off);
            fB[q] = *(const floatx4*)(f2b + off + 4);
        }
        #pragma unroll
        for (int q = 0; q < 4; ++q) {
            const int jc = half * 4 + q;
            int   am[8] = {aA[q].x, aA[q].y, aA[q].z, aA[q].w,
                           aB[q].x, aB[q].y, aB[q].z, aB[q].w};
            float fv[8] = {fA[q][0], fA[q][1], fA[q][2], fA[q][3],
                           fB[q][0], fB[q][1], fB[q][2], fB[q][3]};
            short8 afrag;
            #pragma unroll
            for (int e = 0; e < 8; ++e) {
                float x  = f1i + fv[e];
                x        = fmaxf(x, 0.2f * x);              // leaky relu
                float pe = am[e] ? __expf(x) : 0.f;         // masked exp
                if (e & 1) s1 += pe; else s0 += pe;
                afrag[e] = f2bf(pe);
            }
            pfr[jc] = afrag;
        }
    }

    // ---------- phase 2: h loads (L2-hot) + MFMA, 2-jc chunks ----------
    floatx4 acc0 = {0.f,0.f,0.f,0.f}, acc1 = {0.f,0.f,0.f,0.f};
    floatx4 acc2 = {0.f,0.f,0.f,0.f}, acc3 = {0.f,0.f,0.f,0.f};
    #pragma unroll
    for (int jc = 0; jc < 8; jc += 2) {
        const short* hcA = hb + jc * 2048;
        const short* hcB = hb + (jc + 1) * 2048;
        short8 hA0 = *(const short8*)(hcA);
        short8 hA1 = *(const short8*)(hcA + 512);
        short8 hA2 = *(const short8*)(hcA + 1024);
        short8 hA3 = *(const short8*)(hcA + 1536);
        short8 hB0 = *(const short8*)(hcB);
        short8 hB1 = *(const short8*)(hcB + 512);
        short8 hB2 = *(const short8*)(hcB + 1024);
        short8 hB3 = *(const short8*)(hcB + 1536);

        acc0 = __builtin_amdgcn_mfma_f32_16x16x32_bf16(pfr[jc], hA0, acc0, 0, 0, 0);
        acc1 = __builtin_amdgcn_mfma_f32_16x16x32_bf16(pfr[jc], hA1, acc1, 0, 0, 0);
        acc2 = __builtin_amdgcn_mfma_f32_16x16x32_bf16(pfr[jc], hA2, acc2, 0, 0, 0);
        acc3 = __builtin_amdgcn_mfma_f32_16x16x32_bf16(pfr[jc], hA3, acc3, 0, 0, 0);
        acc0 = __builtin_amdgcn_mfma_f32_16x16x32_bf16(pfr[jc+1], hB0, acc0, 0, 0, 0);
        acc1 = __builtin_amdgcn_mfma_f32_16x16x32_bf16(pfr[jc+1], hB1, acc1, 0, 0, 0);
        acc2 = __builtin_amdgcn_mfma_f32_16x16x32_bf16(pfr[jc+1], hB2, acc2, 0, 0, 0);
        acc3 = __builtin_amdgcn_mfma_f32_16x16x32_bf16(pfr[jc+1], hB3, acc3, 0, 0, 0);
    }

    float s_lane = s0 + s1;
    // per-wave row-subrange denominator: sum over the 4 kg lanes of row iw
    s_lane += __shfl_xor(s_lane, 16, 64);
    s_lane += __shfl_xor(s_lane, 32, 64);
    if (lane < 16) srow[wave][lane] = s_lane;

    floatx4 accs[4] = {acc0, acc1, acc2, acc3};
    #pragma unroll
    for (int fg = 0; fg < 4; ++fg)
        #pragma unroll
        for (int r = 0; r < 4; ++r)
            part[wave][lane][fg * 4 + r] = accs[fg][r];
    __syncthreads();

    // wave w finishes feature-group fg=w for all 16 rows.
    // C layout: value at reg (fg,r) of lane (iw,kg) -> row rloc=kg*4+r, col fg*16+iw
    const int fg = wave;
    float* orow = outp + ((long long)b * N_ + i_base) * F_;
    #pragma unroll
    for (int r = 0; r < 4; ++r) {
        const int idx  = fg * 4 + r;
        const int rloc = kg * 4 + r;
        float tot  = part[0][lane][idx] + part[1][lane][idx]
                   + part[2][lane][idx] + part[3][lane][idx];
        float sden = srow[0][rloc] + srow[1][rloc] + srow[2][rloc] + srow[3][rloc];
        float v = tot / sden;
        v = v > 0.f ? v : (__expf(v) - 1.f);    // ELU (alpha=1)
        orow[(long long)rloc * F_ + fg * 16 + iw] = v;
    }
}

extern "C" void kernel_launch(void* const* d_in, const int* in_sizes, int n_in,
                              void* d_out, int out_size, void* d_ws, size_t ws_size,
                              hipStream_t stream) {
    const float* nf  = (const float*)d_in[0];
    const int*   adj = (const int*)d_in[1];     // bool -> int32 per harness
    const float* W   = (const float*)d_in[2];
    const float* a   = (const float*)d_in[3];
    float* out = (float*)d_out;

    char* ws = (char*)d_ws;
    float* f1    = (float*)ws;                    // 128KB
    float* f2    = (float*)(ws + 131072);         // 128KB
    short* h_swz = (short*)(ws + 262144);         // 4MB

    hipLaunchKernelGGL(gat_prep, dim3(B_ * N_ / 16), dim3(256), 0, stream,
                       nf, W, a, f1, f2, h_swz);
    hipLaunchKernelGGL(gat_attn, dim3(B_ * (N_ / 16)), dim3(256), 0, stream,
                       adj, f1, f2, h_swz, out);
}